// Round 8
// baseline (145.835 us; speedup 1.0000x reference)
//
#include <hip/hip_runtime.h>

// IMM loss: G=8192 groups of M=16 particles, D=64 dims each, fp32.
// terms = Lap(x,x) + Lap(y,y) - 2*Lap(x,y), Lap = exp(-ws[j]*max(||a-b||,EPS)/D).
//
// R10: R9 closed the model — VALUBusy 67% == pure-issue estimate (4.0k
// insts/lane -> 27 us) over dur 41.3 us: the kernel is VALU-COUNT-bound.
// Delete instructions:
//  - Complement trick: XY offsets 9..15 (was 7 DPP + 7 fma per dim) are
//    computed in the complementary lane k as E(k+O'',k), O''=16-O in 1..7,
//    reusing xr_{O''} that ACC_FULL already materializes for gxx. Cost now
//    7 fma, 0 DPP. (Each exp term is globally summed, so WHICH lane
//    computes an ordered entry is irrelevant.) Per-dim 57 -> 50 insts.
//  - Row-split finalize: the 4 db-rows computed 4 identical 56-exp
//    finalizes. Branch on db (uniform per 16-lane row -> no divergence
//    inside a row; DPP row_ror sources all active). ~13 exps/lane.
//    Redundancy 4x -> 1x, so inv_scale = 1/(256*G).
// Staging/swizzle/RED/launch_bounds(256,6) byte-identical to R9
// (absmax=0, no spill, bank-conflicts 0.3% verified).

#define EPS_D 0.006f
#define L2E_D64 0.022542110013890053f   // log2(e)/64
#define EXP2(x) __builtin_amdgcn_exp2f(x)

// Rotate within each 16-lane row by O (O = 1..15, compile-time constant):
// lane j receives the value from lane j+O (mod 16) — verified R2..R9.
#define ROT(v, O) __int_as_float(__builtin_amdgcn_update_dpp(              \
        0, __float_as_int(v), 0x120 + (O), 0xF, 0xF, false))

// Butterfly-xor within 32 lanes via ds_swizzle (BitMode: (xor<<10)|0x1F).
#define SWZ(v, PAT) __int_as_float(__builtin_amdgcn_ds_swizzle(            \
        __float_as_int(v), PAT))
#define XOR16(v) SWZ(v, 0x401F)
#define XOR8(v)  SWZ(v, 0x201F)
#define XOR4(v)  SWZ(v, 0x101F)
#define XOR2(v)  SWZ(v, 0x081F)
#define XOR1(v)  SWZ(v, 0x041F)

__global__ __launch_bounds__(256, 6)
void imm_loss_kernel(const float* __restrict__ ys_t,
                     const float* __restrict__ ys_r,
                     const float* __restrict__ w_scale,
                     const float* __restrict__ time_w,
                     float* __restrict__ partials)
{
    const int tid  = threadIdx.x;
    const int lane = tid & 63;
    const int wave = tid >> 6;
    const int g    = blockIdx.x * 4 + wave;   // one group per wave
    const int j    = lane & 15;               // particle index (DPP axis)
    const int db   = lane >> 4;               // dim-quarter 0..3

    // Per-wave LDS: 256 granules (4KB), reused for x then y.
    __shared__ float4 lds4[4][256];           // 16 KB / block
    __shared__ float smem[4];

    const float4* xg = reinterpret_cast<const float4*>(ys_t + (size_t)g * 1024);
    const float4* yg = reinterpret_cast<const float4*>(ys_r + (size_t)g * 1024);

    const float s_j = w_scale[g * 16 + j] * L2E_D64;  // ws[j]*log2e/D
    const float tw  = time_w[g * 16];                 // uniform per wave

    // Phase 1: load x (coalesced, swizzled source: slot (r,q) gets global
    // granule (r, q^(r&7)) — R6-verified), write LDS, read back this lane's
    // 16 x-dims.
    {
        float4 xs[4];
        #pragma unroll
        for (int k = 0; k < 4; ++k) {
            const int r  = 4 * k + db;
            const int gq = j ^ (r & 7);
            xs[k] = xg[r * 16 + gq];
        }
        #pragma unroll
        for (int k = 0; k < 4; ++k) lds4[wave][k * 64 + lane] = xs[k];
    }

    float xarr[16];
    #pragma unroll
    for (int m = 0; m < 4; ++m) {
        const int sl = (db * 4 + m) ^ (j & 7);
        const float4 v = lds4[wave][j * 16 + sl];
        xarr[4*m+0] = v.x; xarr[4*m+1] = v.y; xarr[4*m+2] = v.z; xarr[4*m+3] = v.w;
    }

    // Phase 2: load y (deferred), overwrite same LDS region (wave-local,
    // compiler orders via lgkm deps; no barrier).
    {
        float4 yv[4];
        #pragma unroll
        for (int k = 0; k < 4; ++k) {
            const int r  = 4 * k + db;
            const int gq = j ^ (r & 7);
            yv[k] = yg[r * 16 + gq];
        }
        #pragma unroll
        for (int k = 0; k < 4; ++k) lds4[wave][k * 64 + lane] = yv[k];
    }

    // Gram accumulators.
    float nx = 0.f, ny = 0.f, g0 = 0.f;
    float gxx[8], gyy[8], gxy[8], hxy2[7];
    #pragma unroll
    for (int i = 0; i < 8; ++i) { gxx[i] = 0.f; gyy[i] = 0.f; gxy[i] = 0.f; }
    #pragma unroll
    for (int i = 0; i < 7; ++i) hxy2[i] = 0.f;

    // O = 1..7: xr serves gxx AND the complement-xy (hxy2); yr serves gyy+gxy.
#define ACC_FULLX(O) {                                                     \
            const float xr = ROT(xd, O);                                   \
            const float yr = ROT(yd, O);                                   \
            gxx[(O)-1]  = fmaf(xr, xd, gxx[(O)-1]);                        \
            gyy[(O)-1]  = fmaf(yr, yd, gyy[(O)-1]);                        \
            gxy[(O)-1]  = fmaf(yr, xd, gxy[(O)-1]);                        \
            hxy2[(O)-1] = fmaf(xr, yd, hxy2[(O)-1]); }
#define ACC_FULL8 {                                                        \
            const float xr = ROT(xd, 8);                                   \
            const float yr = ROT(yd, 8);                                   \
            gxx[7] = fmaf(xr, xd, gxx[7]);                                 \
            gyy[7] = fmaf(yr, yd, gyy[7]);                                 \
            gxy[7] = fmaf(yr, xd, gxy[7]); }

    // Read y granule-at-a-time (4 regs live) and accumulate.
#define GRAM4(M) {                                                         \
        const int sl = (db * 4 + (M)) ^ (j & 7);                           \
        const float4 wv = lds4[wave][j * 16 + sl];                         \
        _Pragma("unroll")                                                  \
        for (int e = 0; e < 4; ++e) {                                      \
            const float xd = xarr[4*(M)+e];                                \
            const float yd = (e == 0) ? wv.x : (e == 1) ? wv.y             \
                           : (e == 2) ? wv.z : wv.w;                       \
            nx = fmaf(xd, xd, nx);                                         \
            ny = fmaf(yd, yd, ny);                                         \
            g0 = fmaf(xd, yd, g0);                                         \
            ACC_FULLX(1) ACC_FULLX(2) ACC_FULLX(3) ACC_FULLX(4)            \
            ACC_FULLX(5) ACC_FULLX(6) ACC_FULLX(7) ACC_FULL8               \
        } }

    GRAM4(0)
    GRAM4(1)
    GRAM4(2)
    GRAM4(3)

    // Reduce partial Gram terms over the 4 dim-quarters (db axis):
    // xor16 (swizzle, within-32) + xor32 (shfl). All lanes get full sums.
#define RED(v) { v += XOR16(v); v += __shfl_xor(v, 32, 64); }
    RED(nx) RED(ny) RED(g0)
    #pragma unroll
    for (int i = 0; i < 8; ++i) { RED(gxx[i]) RED(gyy[i]) RED(gxy[i]) }
    #pragma unroll
    for (int i = 0; i < 7; ++i) { RED(hxy2[i]) }

    // ---- Finalize, ROW-SPLIT: each 16-lane row handles a disjoint offset
    // subset (db uniform per row -> branch is row-uniform, DPP-safe).
    float acc = 0.0f;

    // O = 1..7: FULL(O) (xx,yy,xy at +O) plus complement-xy (entry
    // E(j+O, j) computed here in lane j: sk=s_{j+O}, ddw=||x_{j+O}-y_j||).
#define FIN_PAIR(O) {                                                      \
        const float sk  = ROT(s_j, O);                                     \
        const float nxr = ROT(nx, O);                                      \
        const float nyr = ROT(ny, O);                                      \
        const float ddx = fmaxf(sqrtf(fmaxf(nx + nxr - 2.0f*gxx[(O)-1], 0.f)), EPS_D); \
        const float ddy = fmaxf(sqrtf(fmaxf(ny + nyr - 2.0f*gyy[(O)-1], 0.f)), EPS_D); \
        const float ddz = fmaxf(sqrtf(fmaxf(nx + nyr - 2.0f*gxy[(O)-1], 0.f)), EPS_D); \
        const float ddw = fmaxf(sqrtf(fmaxf(nxr + ny - 2.0f*hxy2[(O)-1], 0.f)), EPS_D); \
        acc += EXP2(-s_j * ddx) + EXP2(-sk * ddx);                         \
        acc += EXP2(-s_j * ddy) + EXP2(-sk * ddy);                         \
        acc -= 2.0f * EXP2(-s_j * ddz);                                    \
        acc -= 2.0f * EXP2(-sk  * ddw); }

    // O = 8: xx/yy double-covered -> 0.5; xy offset-8 appears once -> -2.
#define FIN_F8 {                                                           \
        const float sk  = ROT(s_j, 8);                                     \
        const float nxr = ROT(nx, 8);                                      \
        const float nyr = ROT(ny, 8);                                      \
        const float ddx = fmaxf(sqrtf(fmaxf(nx + nxr - 2.0f*gxx[7], 0.f)), EPS_D); \
        const float ddy = fmaxf(sqrtf(fmaxf(ny + nyr - 2.0f*gyy[7], 0.f)), EPS_D); \
        const float ddz = fmaxf(sqrtf(fmaxf(nx + nyr - 2.0f*gxy[7], 0.f)), EPS_D); \
        acc += 0.5f * (EXP2(-s_j * ddx) + EXP2(-sk * ddx));                \
        acc += 0.5f * (EXP2(-s_j * ddy) + EXP2(-sk * ddy));                \
        acc -= 2.0f * EXP2(-s_j * ddz); }

    if (db == 0)      { FIN_PAIR(1) FIN_PAIR(5) }
    else if (db == 1) { FIN_PAIR(2) FIN_PAIR(6) }
    else if (db == 2) { FIN_PAIR(3) FIN_PAIR(7) }
    else {
        FIN_PAIR(4)
        FIN_F8
        // xx and yy diagonals: d=0 clamps to EPS.
        acc += 2.0f * EXP2(-s_j * EPS_D);
        // offset 0: xy pair (j, j).
        const float d2 = fmaxf(nx + ny - 2.0f * g0, 0.0f);
        const float dd = fmaxf(sqrtf(d2), EPS_D);
        acc -= 2.0f * EXP2(-s_j * dd);
    }

    // 64-lane butterfly: rows hold disjoint subsets -> sum = 1x group term.
    float val = acc * tw;
    val += __shfl_xor(val, 32, 64);
    val += XOR16(val);
    val += XOR8(val);
    val += XOR4(val);
    val += XOR2(val);
    val += XOR1(val);

    if (lane == 0) smem[wave] = val;
    __syncthreads();
    if (tid == 0)
        partials[blockIdx.x] = smem[0] + smem[1] + smem[2] + smem[3];
}

__global__ void imm_reduce_kernel(const float* __restrict__ part, int n,
                                  float inv_scale, float* __restrict__ out)
{
    const int tid = threadIdx.x;
    float v = 0.f;
    for (int i = tid; i < n; i += 256) v += part[i];
    #pragma unroll
    for (int off = 32; off; off >>= 1) v += __shfl_xor(v, off, 64);
    __shared__ float s[4];
    if ((tid & 63) == 0) s[tid >> 6] = v;
    __syncthreads();
    if (tid == 0) out[0] = (s[0] + s[1] + s[2] + s[3]) * inv_scale;
}

extern "C" void kernel_launch(void* const* d_in, const int* in_sizes, int n_in,
                              void* d_out, int out_size, void* d_ws, size_t ws_size,
                              hipStream_t stream)
{
    const float* ys_t = (const float*)d_in[0];
    const float* ys_r = (const float*)d_in[1];
    const float* wsc  = (const float*)d_in[2];
    const float* twp  = (const float*)d_in[3];
    float* out      = (float*)d_out;
    float* partials = (float*)d_ws;

    const int B = in_sizes[2];      // 131072 (w_scale element count)
    const int G = B / 16;           // 8192 groups
    const int blocks = G / 4;       // one group per wave, 4 waves per block

    imm_loss_kernel<<<blocks, 256, 0, stream>>>(ys_t, ys_r, wsc, twp, partials);

    // Rows hold disjoint offset subsets -> partials sum = sum_g(tw_g*terms_g);
    // divide by M*M*G.
    const float inv_scale = 1.0f / (256.0f * (float)G);
    imm_reduce_kernel<<<1, 256, 0, stream>>>(partials, blocks, inv_scale, out);
}

// Round 9
// 117.179 us; speedup vs baseline: 1.2446x; 1.2446x over previous
//
#include <hip/hip_runtime.h>

// IMM loss: G=8192 groups of M=16 particles, D=64 dims each, fp32.
// terms = Lap(x,x) + Lap(y,y) - 2*Lap(x,y), Lap = exp(-ws[j]*max(||a-b||,EPS)/D).
//
// R11 == R10 with ONE change: launch_bounds(256,6) -> (256,4) (VGPR cap
// 85 -> 128). R10 post-mortem: WRITE_SIZE=100MB scratch + VGPR_Count=40
// (below cap!) = allocator demoted accumulator arrays when the complement
// trick's two-consumer DPP results (+~16 peak live in GRAM) pushed pressure
// past 85. R2 precedent: 128-reg kernels run spill-free. R9's MEASURED
// occupancy was ~44% (14 waves/CU) despite 6 declared, so the lower floor
// costs nothing measured.
//
// R10 algebra (verified absmax=0):
//  - Complement trick: XY offsets 9..15 computed in complementary lane as
//    E(k+O'',k) reusing xr from ACC_FULL -> 7 fma, 0 extra DPP per dim.
//  - Row-split finalize: db-rows handle disjoint offset subsets (~13 exps
//    per lane instead of 56); inv_scale = 1/(256*G).

#define EPS_D 0.006f
#define L2E_D64 0.022542110013890053f   // log2(e)/64
#define EXP2(x) __builtin_amdgcn_exp2f(x)

// Rotate within each 16-lane row by O (O = 1..15, compile-time constant):
// lane j receives the value from lane j+O (mod 16) — verified R2..R10.
#define ROT(v, O) __int_as_float(__builtin_amdgcn_update_dpp(              \
        0, __float_as_int(v), 0x120 + (O), 0xF, 0xF, false))

// Butterfly-xor within 32 lanes via ds_swizzle (BitMode: (xor<<10)|0x1F).
#define SWZ(v, PAT) __int_as_float(__builtin_amdgcn_ds_swizzle(            \
        __float_as_int(v), PAT))
#define XOR16(v) SWZ(v, 0x401F)
#define XOR8(v)  SWZ(v, 0x201F)
#define XOR4(v)  SWZ(v, 0x101F)
#define XOR2(v)  SWZ(v, 0x081F)
#define XOR1(v)  SWZ(v, 0x041F)

__global__ __launch_bounds__(256, 4)
void imm_loss_kernel(const float* __restrict__ ys_t,
                     const float* __restrict__ ys_r,
                     const float* __restrict__ w_scale,
                     const float* __restrict__ time_w,
                     float* __restrict__ partials)
{
    const int tid  = threadIdx.x;
    const int lane = tid & 63;
    const int wave = tid >> 6;
    const int g    = blockIdx.x * 4 + wave;   // one group per wave
    const int j    = lane & 15;               // particle index (DPP axis)
    const int db   = lane >> 4;               // dim-quarter 0..3

    // Per-wave LDS: 256 granules (4KB), reused for x then y.
    __shared__ float4 lds4[4][256];           // 16 KB / block
    __shared__ float smem[4];

    const float4* xg = reinterpret_cast<const float4*>(ys_t + (size_t)g * 1024);
    const float4* yg = reinterpret_cast<const float4*>(ys_r + (size_t)g * 1024);

    const float s_j = w_scale[g * 16 + j] * L2E_D64;  // ws[j]*log2e/D
    const float tw  = time_w[g * 16];                 // uniform per wave

    // Phase 1: load x (coalesced, swizzled source: slot (r,q) gets global
    // granule (r, q^(r&7)) — R6-verified), write LDS, read back this lane's
    // 16 x-dims.
    {
        float4 xs[4];
        #pragma unroll
        for (int k = 0; k < 4; ++k) {
            const int r  = 4 * k + db;
            const int gq = j ^ (r & 7);
            xs[k] = xg[r * 16 + gq];
        }
        #pragma unroll
        for (int k = 0; k < 4; ++k) lds4[wave][k * 64 + lane] = xs[k];
    }

    float xarr[16];
    #pragma unroll
    for (int m = 0; m < 4; ++m) {
        const int sl = (db * 4 + m) ^ (j & 7);
        const float4 v = lds4[wave][j * 16 + sl];
        xarr[4*m+0] = v.x; xarr[4*m+1] = v.y; xarr[4*m+2] = v.z; xarr[4*m+3] = v.w;
    }

    // Phase 2: load y (deferred), overwrite same LDS region (wave-local,
    // compiler orders via lgkm deps; no barrier).
    {
        float4 yv[4];
        #pragma unroll
        for (int k = 0; k < 4; ++k) {
            const int r  = 4 * k + db;
            const int gq = j ^ (r & 7);
            yv[k] = yg[r * 16 + gq];
        }
        #pragma unroll
        for (int k = 0; k < 4; ++k) lds4[wave][k * 64 + lane] = yv[k];
    }

    // Gram accumulators.
    float nx = 0.f, ny = 0.f, g0 = 0.f;
    float gxx[8], gyy[8], gxy[8], hxy2[7];
    #pragma unroll
    for (int i = 0; i < 8; ++i) { gxx[i] = 0.f; gyy[i] = 0.f; gxy[i] = 0.f; }
    #pragma unroll
    for (int i = 0; i < 7; ++i) hxy2[i] = 0.f;

    // O = 1..7: xr serves gxx AND the complement-xy (hxy2); yr serves gyy+gxy.
#define ACC_FULLX(O) {                                                     \
            const float xr = ROT(xd, O);                                   \
            const float yr = ROT(yd, O);                                   \
            gxx[(O)-1]  = fmaf(xr, xd, gxx[(O)-1]);                        \
            gyy[(O)-1]  = fmaf(yr, yd, gyy[(O)-1]);                        \
            gxy[(O)-1]  = fmaf(yr, xd, gxy[(O)-1]);                        \
            hxy2[(O)-1] = fmaf(xr, yd, hxy2[(O)-1]); }
#define ACC_FULL8 {                                                        \
            const float xr = ROT(xd, 8);                                   \
            const float yr = ROT(yd, 8);                                   \
            gxx[7] = fmaf(xr, xd, gxx[7]);                                 \
            gyy[7] = fmaf(yr, yd, gyy[7]);                                 \
            gxy[7] = fmaf(yr, xd, gxy[7]); }

    // Read y granule-at-a-time (4 regs live) and accumulate.
#define GRAM4(M) {                                                         \
        const int sl = (db * 4 + (M)) ^ (j & 7);                           \
        const float4 wv = lds4[wave][j * 16 + sl];                         \
        _Pragma("unroll")                                                  \
        for (int e = 0; e < 4; ++e) {                                      \
            const float xd = xarr[4*(M)+e];                                \
            const float yd = (e == 0) ? wv.x : (e == 1) ? wv.y             \
                           : (e == 2) ? wv.z : wv.w;                       \
            nx = fmaf(xd, xd, nx);                                         \
            ny = fmaf(yd, yd, ny);                                         \
            g0 = fmaf(xd, yd, g0);                                         \
            ACC_FULLX(1) ACC_FULLX(2) ACC_FULLX(3) ACC_FULLX(4)            \
            ACC_FULLX(5) ACC_FULLX(6) ACC_FULLX(7) ACC_FULL8               \
        } }

    GRAM4(0)
    GRAM4(1)
    GRAM4(2)
    GRAM4(3)

    // Reduce partial Gram terms over the 4 dim-quarters (db axis):
    // xor16 (swizzle, within-32) + xor32 (shfl). All lanes get full sums.
#define RED(v) { v += XOR16(v); v += __shfl_xor(v, 32, 64); }
    RED(nx) RED(ny) RED(g0)
    #pragma unroll
    for (int i = 0; i < 8; ++i) { RED(gxx[i]) RED(gyy[i]) RED(gxy[i]) }
    #pragma unroll
    for (int i = 0; i < 7; ++i) { RED(hxy2[i]) }

    // ---- Finalize, ROW-SPLIT: each 16-lane row handles a disjoint offset
    // subset (db uniform per row; DPP sources within a row all active).
    float acc = 0.0f;

    // O = 1..7: FULL(O) (xx,yy,xy at +O) plus complement-xy (entry
    // E(j+O, j) computed here in lane j: sk=s_{j+O}, ddw=||x_{j+O}-y_j||).
#define FIN_PAIR(O) {                                                      \
        const float sk  = ROT(s_j, O);                                     \
        const float nxr = ROT(nx, O);                                      \
        const float nyr = ROT(ny, O);                                      \
        const float ddx = fmaxf(sqrtf(fmaxf(nx + nxr - 2.0f*gxx[(O)-1], 0.f)), EPS_D); \
        const float ddy = fmaxf(sqrtf(fmaxf(ny + nyr - 2.0f*gyy[(O)-1], 0.f)), EPS_D); \
        const float ddz = fmaxf(sqrtf(fmaxf(nx + nyr - 2.0f*gxy[(O)-1], 0.f)), EPS_D); \
        const float ddw = fmaxf(sqrtf(fmaxf(nxr + ny - 2.0f*hxy2[(O)-1], 0.f)), EPS_D); \
        acc += EXP2(-s_j * ddx) + EXP2(-sk * ddx);                         \
        acc += EXP2(-s_j * ddy) + EXP2(-sk * ddy);                         \
        acc -= 2.0f * EXP2(-s_j * ddz);                                    \
        acc -= 2.0f * EXP2(-sk  * ddw); }

    // O = 8: xx/yy double-covered -> 0.5; xy offset-8 appears once -> -2.
#define FIN_F8 {                                                           \
        const float sk  = ROT(s_j, 8);                                     \
        const float nxr = ROT(nx, 8);                                      \
        const float nyr = ROT(ny, 8);                                      \
        const float ddx = fmaxf(sqrtf(fmaxf(nx + nxr - 2.0f*gxx[7], 0.f)), EPS_D); \
        const float ddy = fmaxf(sqrtf(fmaxf(ny + nyr - 2.0f*gyy[7], 0.f)), EPS_D); \
        const float ddz = fmaxf(sqrtf(fmaxf(nx + nyr - 2.0f*gxy[7], 0.f)), EPS_D); \
        acc += 0.5f * (EXP2(-s_j * ddx) + EXP2(-sk * ddx));                \
        acc += 0.5f * (EXP2(-s_j * ddy) + EXP2(-sk * ddy));                \
        acc -= 2.0f * EXP2(-s_j * ddz); }

    if (db == 0)      { FIN_PAIR(1) FIN_PAIR(5) }
    else if (db == 1) { FIN_PAIR(2) FIN_PAIR(6) }
    else if (db == 2) { FIN_PAIR(3) FIN_PAIR(7) }
    else {
        FIN_PAIR(4)
        FIN_F8
        // xx and yy diagonals: d=0 clamps to EPS.
        acc += 2.0f * EXP2(-s_j * EPS_D);
        // offset 0: xy pair (j, j).
        const float d2 = fmaxf(nx + ny - 2.0f * g0, 0.0f);
        const float dd = fmaxf(sqrtf(d2), EPS_D);
        acc -= 2.0f * EXP2(-s_j * dd);
    }

    // 64-lane butterfly: rows hold disjoint subsets -> sum = 1x group term.
    float val = acc * tw;
    val += __shfl_xor(val, 32, 64);
    val += XOR16(val);
    val += XOR8(val);
    val += XOR4(val);
    val += XOR2(val);
    val += XOR1(val);

    if (lane == 0) smem[wave] = val;
    __syncthreads();
    if (tid == 0)
        partials[blockIdx.x] = smem[0] + smem[1] + smem[2] + smem[3];
}

__global__ void imm_reduce_kernel(const float* __restrict__ part, int n,
                                  float inv_scale, float* __restrict__ out)
{
    const int tid = threadIdx.x;
    float v = 0.f;
    for (int i = tid; i < n; i += 256) v += part[i];
    #pragma unroll
    for (int off = 32; off; off >>= 1) v += __shfl_xor(v, off, 64);
    __shared__ float s[4];
    if ((tid & 63) == 0) s[tid >> 6] = v;
    __syncthreads();
    if (tid == 0) out[0] = (s[0] + s[1] + s[2] + s[3]) * inv_scale;
}

extern "C" void kernel_launch(void* const* d_in, const int* in_sizes, int n_in,
                              void* d_out, int out_size, void* d_ws, size_t ws_size,
                              hipStream_t stream)
{
    const float* ys_t = (const float*)d_in[0];
    const float* ys_r = (const float*)d_in[1];
    const float* wsc  = (const float*)d_in[2];
    const float* twp  = (const float*)d_in[3];
    float* out      = (float*)d_out;
    float* partials = (float*)d_ws;

    const int B = in_sizes[2];      // 131072 (w_scale element count)
    const int G = B / 16;           // 8192 groups
    const int blocks = G / 4;       // one group per wave, 4 waves per block

    imm_loss_kernel<<<blocks, 256, 0, stream>>>(ys_t, ys_r, wsc, twp, partials);

    // Rows hold disjoint offset subsets -> partials sum = sum_g(tw_g*terms_g);
    // divide by M*M*G.
    const float inv_scale = 1.0f / (256.0f * (float)G);
    imm_reduce_kernel<<<1, 256, 0, stream>>>(partials, blocks, inv_scale, out);
}

// Round 10
// 114.872 us; speedup vs baseline: 1.2695x; 1.0201x over previous
//
#include <hip/hip_runtime.h>

// IMM loss: G=8192 groups of M=16 particles, D=64 dims each, fp32.
// terms = Lap(x,x) + Lap(y,y) - 2*Lap(x,y), Lap = exp(-ws[j]*max(||a-b||,EPS)/D).
//
// R12: GRAM issue-slot reduction (R11 verified at ~33us loss, no spill).
//  - ROT bound_ctrl false->true: update_dpp(old=0,bc=0) forces an old-init
//    mov per DPP (LLVM can't prove old dead); bc=1 writes every enabled
//    lane (sources never invalid for row_ror) -> old provably dead ->
//    single v_mov_b32_dpp, foldable by GCNDPPCombine. Same semantics.
//  - GRAM in float2 pairs with __builtin_elementwise_fma -> v_pk_fma_f32
//    (gfx950 packed fp32): 34 scalar fma/dim -> 17 pk slots. DPP per
//    32-bit half (count unchanged). Accumulators are float2, folded to
//    scalar before the unchanged RED/finalize.
// Staging/swizzle/RED/row-split finalize/launch_bounds(256,4) identical to
// R11 (absmax=0, WRITE=64KB verified).

#define EPS_D 0.006f
#define L2E_D64 0.022542110013890053f   // log2(e)/64
#define EXP2(x) __builtin_amdgcn_exp2f(x)

typedef float f2 __attribute__((ext_vector_type(2)));
#define PKFMA(a, b, c) __builtin_elementwise_fma((a), (b), (c))

// Rotate within each 16-lane row by O (O = 1..15, compile-time constant):
// lane j receives the value from lane j+O (mod 16) — verified R2..R11.
// bound_ctrl=true: identical result (sources always valid), old elided.
#define ROT(v, O) __int_as_float(__builtin_amdgcn_update_dpp(              \
        0, __float_as_int(v), 0x120 + (O), 0xF, 0xF, true))

// Butterfly-xor within 32 lanes via ds_swizzle (BitMode: (xor<<10)|0x1F).
#define SWZ(v, PAT) __int_as_float(__builtin_amdgcn_ds_swizzle(            \
        __float_as_int(v), PAT))
#define XOR16(v) SWZ(v, 0x401F)
#define XOR8(v)  SWZ(v, 0x201F)
#define XOR4(v)  SWZ(v, 0x101F)
#define XOR2(v)  SWZ(v, 0x081F)
#define XOR1(v)  SWZ(v, 0x041F)

__global__ __launch_bounds__(256, 4)
void imm_loss_kernel(const float* __restrict__ ys_t,
                     const float* __restrict__ ys_r,
                     const float* __restrict__ w_scale,
                     const float* __restrict__ time_w,
                     float* __restrict__ partials)
{
    const int tid  = threadIdx.x;
    const int lane = tid & 63;
    const int wave = tid >> 6;
    const int g    = blockIdx.x * 4 + wave;   // one group per wave
    const int j    = lane & 15;               // particle index (DPP axis)
    const int db   = lane >> 4;               // dim-quarter 0..3

    // Per-wave LDS: 256 granules (4KB), reused for x then y.
    __shared__ float4 lds4[4][256];           // 16 KB / block
    __shared__ float smem[4];

    const float4* xg = reinterpret_cast<const float4*>(ys_t + (size_t)g * 1024);
    const float4* yg = reinterpret_cast<const float4*>(ys_r + (size_t)g * 1024);

    const float s_j = w_scale[g * 16 + j] * L2E_D64;  // ws[j]*log2e/D
    const float tw  = time_w[g * 16];                 // uniform per wave

    // Phase 1: load x (coalesced, swizzled source: slot (r,q) gets global
    // granule (r, q^(r&7)) — R6-verified), write LDS, read back this lane's
    // 16 x-dims as 8 float2 pairs.
    {
        float4 xs[4];
        #pragma unroll
        for (int k = 0; k < 4; ++k) {
            const int r  = 4 * k + db;
            const int gq = j ^ (r & 7);
            xs[k] = xg[r * 16 + gq];
        }
        #pragma unroll
        for (int k = 0; k < 4; ++k) lds4[wave][k * 64 + lane] = xs[k];
    }

    f2 xarr2[8];
    #pragma unroll
    for (int m = 0; m < 4; ++m) {
        const int sl = (db * 4 + m) ^ (j & 7);
        const float4 v = lds4[wave][j * 16 + sl];
        xarr2[2*m+0] = f2{v.x, v.y};
        xarr2[2*m+1] = f2{v.z, v.w};
    }

    // Phase 2: load y (deferred), overwrite same LDS region (wave-local,
    // compiler orders via lgkm deps; no barrier).
    {
        float4 yv[4];
        #pragma unroll
        for (int k = 0; k < 4; ++k) {
            const int r  = 4 * k + db;
            const int gq = j ^ (r & 7);
            yv[k] = yg[r * 16 + gq];
        }
        #pragma unroll
        for (int k = 0; k < 4; ++k) lds4[wave][k * 64 + lane] = yv[k];
    }

    // Gram accumulators (packed pairs; folded to scalar before RED).
    f2 nx2 = {0.f, 0.f}, ny2 = {0.f, 0.f}, g02 = {0.f, 0.f};
    f2 gxx2[8], gyy2[8], gxy2[8], hxy22[7];
    #pragma unroll
    for (int i = 0; i < 8; ++i) {
        gxx2[i] = f2{0.f, 0.f}; gyy2[i] = f2{0.f, 0.f}; gxy2[i] = f2{0.f, 0.f};
    }
    #pragma unroll
    for (int i = 0; i < 7; ++i) hxy22[i] = f2{0.f, 0.f};

    // O = 1..7: xr serves gxx AND the complement-xy (hxy2); yr serves gyy+gxy.
#define ACC_FULLX(O) {                                                     \
            f2 xr2, yr2;                                                   \
            xr2.x = ROT(xd2.x, O); xr2.y = ROT(xd2.y, O);                  \
            yr2.x = ROT(yd2.x, O); yr2.y = ROT(yd2.y, O);                  \
            gxx2[(O)-1]  = PKFMA(xr2, xd2, gxx2[(O)-1]);                   \
            gyy2[(O)-1]  = PKFMA(yr2, yd2, gyy2[(O)-1]);                   \
            gxy2[(O)-1]  = PKFMA(yr2, xd2, gxy2[(O)-1]);                   \
            hxy22[(O)-1] = PKFMA(xr2, yd2, hxy22[(O)-1]); }
#define ACC_FULL8 {                                                        \
            f2 xr2, yr2;                                                   \
            xr2.x = ROT(xd2.x, 8); xr2.y = ROT(xd2.y, 8);                  \
            yr2.x = ROT(yd2.x, 8); yr2.y = ROT(yd2.y, 8);                  \
            gxx2[7] = PKFMA(xr2, xd2, gxx2[7]);                            \
            gyy2[7] = PKFMA(yr2, yd2, gyy2[7]);                            \
            gxy2[7] = PKFMA(yr2, xd2, gxy2[7]); }

#define PROC_PAIR(XD, YD) {                                                \
            const f2 xd2 = (XD), yd2 = (YD);                               \
            nx2 = PKFMA(xd2, xd2, nx2);                                    \
            ny2 = PKFMA(yd2, yd2, ny2);                                    \
            g02 = PKFMA(xd2, yd2, g02);                                    \
            ACC_FULLX(1) ACC_FULLX(2) ACC_FULLX(3) ACC_FULLX(4)            \
            ACC_FULLX(5) ACC_FULLX(6) ACC_FULLX(7) ACC_FULL8 }

    // Read y granule-at-a-time and accumulate (2 pairs per granule).
#define GRAM4(M) {                                                         \
        const int sl = (db * 4 + (M)) ^ (j & 7);                           \
        const float4 wv = lds4[wave][j * 16 + sl];                         \
        PROC_PAIR(xarr2[2*(M)+0], (f2{wv.x, wv.y}))                        \
        PROC_PAIR(xarr2[2*(M)+1], (f2{wv.z, wv.w})) }

    GRAM4(0)
    GRAM4(1)
    GRAM4(2)
    GRAM4(3)

    // Fold packed pairs to scalars.
    float nx = nx2.x + nx2.y, ny = ny2.x + ny2.y, g0 = g02.x + g02.y;
    float gxx[8], gyy[8], gxy[8], hxy2[7];
    #pragma unroll
    for (int i = 0; i < 8; ++i) {
        gxx[i] = gxx2[i].x + gxx2[i].y;
        gyy[i] = gyy2[i].x + gyy2[i].y;
        gxy[i] = gxy2[i].x + gxy2[i].y;
    }
    #pragma unroll
    for (int i = 0; i < 7; ++i) hxy2[i] = hxy22[i].x + hxy22[i].y;

    // Reduce partial Gram terms over the 4 dim-quarters (db axis):
    // xor16 (swizzle, within-32) + xor32 (shfl). All lanes get full sums.
#define RED(v) { v += XOR16(v); v += __shfl_xor(v, 32, 64); }
    RED(nx) RED(ny) RED(g0)
    #pragma unroll
    for (int i = 0; i < 8; ++i) { RED(gxx[i]) RED(gyy[i]) RED(gxy[i]) }
    #pragma unroll
    for (int i = 0; i < 7; ++i) { RED(hxy2[i]) }

    // ---- Finalize, ROW-SPLIT: each 16-lane row handles a disjoint offset
    // subset (db uniform per row; DPP sources within a row all active).
    float acc = 0.0f;

    // O = 1..7: FULL(O) (xx,yy,xy at +O) plus complement-xy (entry
    // E(j+O, j) computed here in lane j: sk=s_{j+O}, ddw=||x_{j+O}-y_j||).
#define FIN_PAIR(O) {                                                      \
        const float sk  = ROT(s_j, O);                                     \
        const float nxr = ROT(nx, O);                                      \
        const float nyr = ROT(ny, O);                                      \
        const float ddx = fmaxf(sqrtf(fmaxf(nx + nxr - 2.0f*gxx[(O)-1], 0.f)), EPS_D); \
        const float ddy = fmaxf(sqrtf(fmaxf(ny + nyr - 2.0f*gyy[(O)-1], 0.f)), EPS_D); \
        const float ddz = fmaxf(sqrtf(fmaxf(nx + nyr - 2.0f*gxy[(O)-1], 0.f)), EPS_D); \
        const float ddw = fmaxf(sqrtf(fmaxf(nxr + ny - 2.0f*hxy2[(O)-1], 0.f)), EPS_D); \
        acc += EXP2(-s_j * ddx) + EXP2(-sk * ddx);                         \
        acc += EXP2(-s_j * ddy) + EXP2(-sk * ddy);                         \
        acc -= 2.0f * EXP2(-s_j * ddz);                                    \
        acc -= 2.0f * EXP2(-sk  * ddw); }

    // O = 8: xx/yy double-covered -> 0.5; xy offset-8 appears once -> -2.
#define FIN_F8 {                                                           \
        const float sk  = ROT(s_j, 8);                                     \
        const float nxr = ROT(nx, 8);                                      \
        const float nyr = ROT(ny, 8);                                      \
        const float ddx = fmaxf(sqrtf(fmaxf(nx + nxr - 2.0f*gxx[7], 0.f)), EPS_D); \
        const float ddy = fmaxf(sqrtf(fmaxf(ny + nyr - 2.0f*gyy[7], 0.f)), EPS_D); \
        const float ddz = fmaxf(sqrtf(fmaxf(nx + nyr - 2.0f*gxy[7], 0.f)), EPS_D); \
        acc += 0.5f * (EXP2(-s_j * ddx) + EXP2(-sk * ddx));                \
        acc += 0.5f * (EXP2(-s_j * ddy) + EXP2(-sk * ddy));                \
        acc -= 2.0f * EXP2(-s_j * ddz); }

    if (db == 0)      { FIN_PAIR(1) FIN_PAIR(5) }
    else if (db == 1) { FIN_PAIR(2) FIN_PAIR(6) }
    else if (db == 2) { FIN_PAIR(3) FIN_PAIR(7) }
    else {
        FIN_PAIR(4)
        FIN_F8
        // xx and yy diagonals: d=0 clamps to EPS.
        acc += 2.0f * EXP2(-s_j * EPS_D);
        // offset 0: xy pair (j, j).
        const float d2 = fmaxf(nx + ny - 2.0f * g0, 0.0f);
        const float dd = fmaxf(sqrtf(d2), EPS_D);
        acc -= 2.0f * EXP2(-s_j * dd);
    }

    // 64-lane butterfly: rows hold disjoint subsets -> sum = 1x group term.
    float val = acc * tw;
    val += __shfl_xor(val, 32, 64);
    val += XOR16(val);
    val += XOR8(val);
    val += XOR4(val);
    val += XOR2(val);
    val += XOR1(val);

    if (lane == 0) smem[wave] = val;
    __syncthreads();
    if (tid == 0)
        partials[blockIdx.x] = smem[0] + smem[1] + smem[2] + smem[3];
}

__global__ void imm_reduce_kernel(const float* __restrict__ part, int n,
                                  float inv_scale, float* __restrict__ out)
{
    const int tid = threadIdx.x;
    float v = 0.f;
    for (int i = tid; i < n; i += 256) v += part[i];
    #pragma unroll
    for (int off = 32; off; off >>= 1) v += __shfl_xor(v, off, 64);
    __shared__ float s[4];
    if ((tid & 63) == 0) s[tid >> 6] = v;
    __syncthreads();
    if (tid == 0) out[0] = (s[0] + s[1] + s[2] + s[3]) * inv_scale;
}

extern "C" void kernel_launch(void* const* d_in, const int* in_sizes, int n_in,
                              void* d_out, int out_size, void* d_ws, size_t ws_size,
                              hipStream_t stream)
{
    const float* ys_t = (const float*)d_in[0];
    const float* ys_r = (const float*)d_in[1];
    const float* wsc  = (const float*)d_in[2];
    const float* twp  = (const float*)d_in[3];
    float* out      = (float*)d_out;
    float* partials = (float*)d_ws;

    const int B = in_sizes[2];      // 131072 (w_scale element count)
    const int G = B / 16;           // 8192 groups
    const int blocks = G / 4;       // one group per wave, 4 waves per block

    imm_loss_kernel<<<blocks, 256, 0, stream>>>(ys_t, ys_r, wsc, twp, partials);

    // Rows hold disjoint offset subsets -> partials sum = sum_g(tw_g*terms_g);
    // divide by M*M*G.
    const float inv_scale = 1.0f / (256.0f * (float)G);
    imm_reduce_kernel<<<1, 256, 0, stream>>>(partials, blocks, inv_scale, out);
}